// Round 19
// baseline (78.496 us; speedup 1.0000x reference)
//
#include <hip/hip_runtime.h>
#include <hip/hip_cooperative_groups.h>

namespace cg = cooperative_groups;

#define NN 128
#define DD 128
#define LL 512
#define FFH 512
#define TANH1 0.76159415595576489f

typedef __attribute__((ext_vector_type(8))) short bf16x8;
typedef __attribute__((ext_vector_type(4))) float f32x4;

struct alignas(16) f4arr { float v[4]; };

__device__ __forceinline__ unsigned short f2bf(float f) {
    union { float f; unsigned u; } v; v.f = f;
    return (unsigned short)((v.u + 0x7FFFu + ((v.u >> 16) & 1u)) >> 16);
}

// ---------------------------------------------------------------------------
// k_coop: ONE cooperative dispatch, 256 blocks x 512 thr (1 block/CU,
// co-residency guaranteed by cooperative launch -> grid.sync() is safe).
// Phase A: block i preps fragment-group i (W1f/W2f) + computes its 8 score
//          rows (thread = 1 of 512 columns) -> c_ws.     [validated math]
// grid.sync()
// Phase B: R14 kB body verbatim (full fragment prefetch, MFMA FFN).
// ---------------------------------------------------------------------------
__global__ __launch_bounds__(512, 2) void k_coop(
    const float* __restrict__ in_obs,
    const float* __restrict__ Wk_w,
    const float* __restrict__ Wk_b,
    const float* __restrict__ wv_w,
    const float* __restrict__ ff1_w,
    const float* __restrict__ ff2_w,
    const float* __restrict__ g1, const float* __restrict__ b1,
    const float* __restrict__ ff1_b,
    const float* __restrict__ ff2_b,
    const float* __restrict__ g2, const float* __restrict__ b2,
    unsigned short* __restrict__ W1f,
    unsigned short* __restrict__ W2f,
    float* __restrict__ c_ws,
    float* __restrict__ out)
{
    const int t = threadIdx.x;
    const int blk = blockIdx.x;
    const int wave = t >> 6, lane = t & 63;
    const int l15 = lane & 15, l4 = lane >> 4;

    __shared__ float row_lds[8][128];
    __shared__ float red[8][8];
    __shared__ float part[8][128];
    __shared__ alignas(16) unsigned short res_lds[16 * 128];
    __shared__ alignas(16) unsigned short h_lds[16 * 512];
    __shared__ alignas(16) float o2_lds[16 * 128];

    // ================= Phase A1: prep fragment-group fg = blk ==============
    {
        const int fl = t >> 3;                 // frag lane 0..63
        const int j  = t & 7;
        const int fl15 = fl & 15, fl4 = fl >> 4;
        if (blk < 128) {
            const int ks = blk & 3, mt = blk >> 2;
            W1f[(blk * 64 + fl) * 8 + j] =
                f2bf(ff1_w[(ks * 32 + fl4 * 8 + j) * FFH + mt * 16 + fl15]);
        } else {
            const int fg = blk - 128;
            const int ks = fg & 15, mt = fg >> 4;
            W2f[(fg * 64 + fl) * 8 + j] =
                f2bf(ff2_w[(ks * 32 + fl4 * 8 + j) * DD + mt * 16 + fl15]);
        }
    }

    // ================= Phase A2: scores rows blk*8 .. +7 ===================
    {
        const int row0 = blk * 8;
        const float* src = in_obs + row0 * DD;
        #pragma unroll
        for (int i = 0; i < 2; ++i) {
            const int idx = t + i * 512;
            row_lds[idx >> 7][idx & 127] = src[idx];
        }
        __syncthreads();

        const int l = t;                       // column 0..511
        float acc[8];
        #pragma unroll
        for (int r = 0; r < 8; ++r) acc[r] = 0.f;
        #pragma unroll 4
        for (int d = 0; d < 128; d += 4) {
            f4arr rb[8];
            #pragma unroll
            for (int r = 0; r < 8; ++r)
                rb[r] = *(const f4arr*)&row_lds[r][d];
            #pragma unroll
            for (int dd = 0; dd < 4; ++dd) {
                const float w = Wk_w[(d + dd) * LL + l];
                #pragma unroll
                for (int r = 0; r < 8; ++r)
                    acc[r] += rb[r].v[dd] * w;
            }
        }
        const float kb = Wk_b[l];
        const float wv = wv_w[640 + l];
        float v[8];
        #pragma unroll
        for (int r = 0; r < 8; ++r)
            v[r] = tanhf(acc[r] + kb) * wv;
        #pragma unroll
        for (int off = 32; off > 0; off >>= 1) {
            #pragma unroll
            for (int r = 0; r < 8; ++r)
                v[r] += __shfl_down(v[r], off, 64);
        }
        if (lane == 0) {
            #pragma unroll
            for (int r = 0; r < 8; ++r) red[r][wave] = v[r];
        }
        __syncthreads();
        if (t < 8) {
            float s = TANH1 * wv_w[1152 + ((row0 + t) & (NN - 1))];
            #pragma unroll
            for (int g = 0; g < 8; ++g) s += red[t][g];
            c_ws[row0 + t] = s;
        }
    }

    // ================= grid-wide barrier (execution + memory) ==============
    __threadfence();
    cg::this_grid().sync();

    // ================= Phase B: R14 kB body (validated) ====================
    const int b = blk >> 4;
    const int j0 = (blk & 15) * 8;

    // ---- full fragment prefetch (32 b128 loads, back-to-back)
    bf16x8 a1p[16];
    #pragma unroll
    for (int i = 0; i < 4; ++i)
        #pragma unroll
        for (int ks = 0; ks < 4; ++ks)
            a1p[i * 4 + ks] =
                *(const bf16x8*)(W1f + (((wave * 4 + i) * 4 + ks) * 64 + lane) * 8);
    bf16x8 a2p[16];
    #pragma unroll
    for (int ks = 0; ks < 16; ++ks)
        a2p[ks] = *(const bf16x8*)(W2f + ((wave * 16 + ks) * 64 + lane) * 8);

    // ---- softmax fully in registers (per wave; q-side term cancels)
    const float cv0 = c_ws[b * NN + lane];
    const float cv1 = c_ws[b * NN + lane + 64];
    float mx = fmaxf(cv0, cv1);
    #pragma unroll
    for (int off = 32; off > 0; off >>= 1) mx = fmaxf(mx, __shfl_xor(mx, off, 64));
    float e0 = __expf(cv0 - mx), e1 = __expf(cv1 - mx);
    float sm = e0 + e1;
    #pragma unroll
    for (int off = 32; off > 0; off >>= 1) sm += __shfl_xor(sm, off, 64);
    const float inv = 1.f / sm;
    e0 *= inv; e1 *= inv;

    // ---- attn partials: wave w sums its 16 j's, both d-halves
    {
        const float* base = in_obs + (b * NN + wave * 16) * DD;
        float a0 = 0.f, a1 = 0.f;
        #pragma unroll
        for (int jj = 0; jj < 16; ++jj) {
            const int js = wave * 16 + jj;
            const float wj = (wave < 4) ? __shfl(e0, js, 64)
                                        : __shfl(e1, js - 64, 64);
            a0 += wj * base[jj * DD + lane];
            a1 += wj * base[jj * DD + 64 + lane];
        }
        part[wave][lane] = a0;
        part[wave][lane + 64] = a1;
    }
    __syncthreads();                               // B1

    // ---- residual + LN1 -> res_lds bf16 (wave w = row w; pad row w+8)
    {
        const int r = wave;
        const int row = b * NN + j0 + r;
        const int c0i = lane * 2;
        const float2 xo = *(const float2*)&in_obs[row * DD + c0i];
        float x0 = xo.x, x1 = xo.y;
        #pragma unroll
        for (int g = 0; g < 8; ++g) {
            const float2 p = *(const float2*)&part[g][c0i];
            x0 += p.x; x1 += p.y;
        }
        float s = x0 + x1;
        #pragma unroll
        for (int off = 32; off > 0; off >>= 1) s += __shfl_xor(s, off, 64);
        const float mu = s * (1.f / 128.f);
        const float d0 = x0 - mu, d1 = x1 - mu;
        float vs = d0 * d0 + d1 * d1;
        #pragma unroll
        for (int off = 32; off > 0; off >>= 1) vs += __shfl_xor(vs, off, 64);
        const float rstd = rsqrtf(vs * (1.f / 128.f) + 1e-5f);
        const float2 gv = *(const float2*)&g1[c0i];
        const float2 bv = *(const float2*)&b1[c0i];
        const float r0 = d0 * rstd * gv.x + bv.x;
        const float r1 = d1 * rstd * gv.y + bv.y;
        const unsigned pk = (unsigned)f2bf(r0) | ((unsigned)f2bf(r1) << 16);
        const int swz = (lane * 4) ^ ((r & 7) << 4);
        *(unsigned*)((char*)res_lds + r * 256 + swz) = pk;
        *(unsigned*)((char*)res_lds + (r + 8) * 256 + (lane * 4)) = 0u; // pad
    }
    __syncthreads();                               // B2

    // ---- FF1 swapped GEMM: wave does mt = wave*4 + {0..3}, frags in regs
    {
        bf16x8 bfrag[4];
        #pragma unroll
        for (int ks = 0; ks < 4; ++ks) {
            const int off = l15 * 256 + ((ks * 64 + l4 * 16) ^ ((l15 & 7) << 4));
            bfrag[ks] = *(const bf16x8*)((const char*)res_lds + off);
        }
        #pragma unroll
        for (int i = 0; i < 4; ++i) {
            const int mt = wave * 4 + i;
            f32x4 acc = {0.f, 0.f, 0.f, 0.f};
            #pragma unroll
            for (int ks = 0; ks < 4; ++ks)
                acc = __builtin_amdgcn_mfma_f32_16x16x32_bf16(
                          a1p[i * 4 + ks], bfrag[ks], acc, 0, 0, 0);
            const f4arr bias = *(const f4arr*)&ff1_b[mt * 16 + l4 * 4];
            uint2 pk;
            pk.x = (unsigned)f2bf(fmaxf(acc[0] + bias.v[0], 0.f))
                 | ((unsigned)f2bf(fmaxf(acc[1] + bias.v[1], 0.f)) << 16);
            pk.y = (unsigned)f2bf(fmaxf(acc[2] + bias.v[2], 0.f))
                 | ((unsigned)f2bf(fmaxf(acc[3] + bias.v[3], 0.f)) << 16);
            const int off = l15 * 1024 + ((mt * 32 + l4 * 8) ^ ((l15 & 7) << 4));
            *(uint2*)((char*)h_lds + off) = pk;
        }
    }
    __syncthreads();                               // B3

    // ---- FF2 swapped GEMM: wave = n-tile (0..7), full K, frags in regs
    {
        f32x4 acc = {0.f, 0.f, 0.f, 0.f};
        #pragma unroll
        for (int ks = 0; ks < 16; ++ks) {
            const int off = l15 * 1024 + ((ks * 64 + l4 * 16) ^ ((l15 & 7) << 4));
            const bf16x8 bfrag = *(const bf16x8*)((const char*)h_lds + off);
            acc = __builtin_amdgcn_mfma_f32_16x16x32_bf16(a2p[ks], bfrag, acc, 0, 0, 0);
        }
        const int off = l15 * 512 + ((wave * 64 + l4 * 16) ^ ((l15 & 7) << 4));
        *(f32x4*)((char*)o2_lds + off) = acc;
    }
    __syncthreads();                               // B4

    // ---- bias + residual + LN2 -> out (wave w = row w)
    {
        const int r = wave;
        const int row = b * NN + j0 + r;
        const int c0i = lane * 2;
        const int off = r * 512 + ((lane * 8) ^ ((r & 7) << 4));
        const float2 o2 = *(const float2*)((char*)o2_lds + off);
        const float2 fb = *(const float2*)&ff2_b[c0i];
        const float2 xo = *(const float2*)&in_obs[row * DD + c0i];
        const float f0 = o2.x + fb.x + xo.x;
        const float f1 = o2.y + fb.y + xo.y;
        float s = f0 + f1;
        #pragma unroll
        for (int off2 = 32; off2 > 0; off2 >>= 1) s += __shfl_xor(s, off2, 64);
        const float mu = s * (1.f / 128.f);
        const float d0 = f0 - mu, d1 = f1 - mu;
        float vs = d0 * d0 + d1 * d1;
        #pragma unroll
        for (int off2 = 32; off2 > 0; off2 >>= 1) vs += __shfl_xor(vs, off2, 64);
        const float rstd = rsqrtf(vs * (1.f / 128.f) + 1e-5f);
        const float2 gv = *(const float2*)&g2[c0i];
        const float2 bv = *(const float2*)&b2[c0i];
        float2 o;
        o.x = d0 * rstd * gv.x + bv.x;
        o.y = d1 * rstd * gv.y + bv.y;
        *(float2*)&out[row * DD + c0i] = o;
    }
}

extern "C" void kernel_launch(void* const* d_in, const int* in_sizes, int n_in,
                              void* d_out, int out_size, void* d_ws, size_t ws_size,
                              hipStream_t stream) {
    const float* in_obs = (const float*)d_in[0];
    // d_in[1] Wq_w, d_in[2] Wq_b, d_in[6] wv_b: dead (cancel in softmax)
    const float* Wk_w  = (const float*)d_in[3];
    const float* Wk_b  = (const float*)d_in[4];
    const float* wv_w  = (const float*)d_in[5];
    const float* g1    = (const float*)d_in[7];
    const float* b1    = (const float*)d_in[8];
    const float* ff1_w = (const float*)d_in[9];
    const float* ff1_b = (const float*)d_in[10];
    const float* ff2_w = (const float*)d_in[11];
    const float* ff2_b = (const float*)d_in[12];
    const float* g2    = (const float*)d_in[13];
    const float* b2    = (const float*)d_in[14];
    float* outp = (float*)d_out;

    unsigned short* W1f = (unsigned short*)d_ws;              // 128 KB
    unsigned short* W2f = W1f + 65536;                        // 128 KB
    float* c_ws = (float*)((char*)d_ws + 262144);             // 8 KB

    void* args[] = {
        (void*)&in_obs, (void*)&Wk_w, (void*)&Wk_b, (void*)&wv_w,
        (void*)&ff1_w, (void*)&ff2_w, (void*)&g1, (void*)&b1,
        (void*)&ff1_b, (void*)&ff2_b, (void*)&g2, (void*)&b2,
        (void*)&W1f, (void*)&W2f, (void*)&c_ws, (void*)&outp
    };
    hipLaunchCooperativeKernel((const void*)k_coop, dim3(256), dim3(512),
                               args, 0, stream);
}

// Round 20
// 25.884 us; speedup vs baseline: 3.0327x; 3.0327x over previous
//
#include <hip/hip_runtime.h>

#define NN 128
#define DD 128
#define LL 512
#define FFH 512
#define TANH1 0.76159415595576489f

typedef __attribute__((ext_vector_type(8))) short bf16x8;
typedef __attribute__((ext_vector_type(4))) float f32x4;

struct alignas(16) f4arr { float v[4]; };

__device__ __forceinline__ unsigned short f2bf(float f) {
    union { float f; unsigned u; } v; v.f = f;
    return (unsigned short)((v.u + 0x7FFFu + ((v.u >> 16) & 1u)) >> 16);
}

// ---------------------------------------------------------------------------
// kA: blocks 0-255 -> scores (R1 form); blocks 256-511 -> weight relayout
// (R5 form). Verbatim R14 (best-measured config: 25.9 us total).
// ---------------------------------------------------------------------------
__global__ __launch_bounds__(256) void kA(
    const float* __restrict__ in_obs,
    const float* __restrict__ Wk_w,
    const float* __restrict__ Wk_b,
    const float* __restrict__ wv_w,
    const float* __restrict__ ff1_w,
    const float* __restrict__ ff2_w,
    float* __restrict__ c_out,
    unsigned short* __restrict__ W1f,
    unsigned short* __restrict__ W2f)
{
    const int t = threadIdx.x;
    const int wave = t >> 6, lane = t & 63;

    if (blockIdx.x >= 256) {
        const int bi = blockIdx.x - 256;
        const int fg = bi & 127;
        const int jp = t >> 6;
        const int l15 = lane & 15, l4 = lane >> 4;
        const int j = jp * 2;
        unsigned short v0, v1;
        unsigned short* dst;
        if (bi < 128) {
            const int ks = fg & 3, mt = fg >> 2;
            v0 = f2bf(ff1_w[(ks * 32 + l4 * 8 + j    ) * FFH + mt * 16 + l15]);
            v1 = f2bf(ff1_w[(ks * 32 + l4 * 8 + j + 1) * FFH + mt * 16 + l15]);
            dst = W1f;
        } else {
            const int ks = fg & 15, mt = fg >> 4;
            v0 = f2bf(ff2_w[(ks * 32 + l4 * 8 + j    ) * DD + mt * 16 + l15]);
            v1 = f2bf(ff2_w[(ks * 32 + l4 * 8 + j + 1) * DD + mt * 16 + l15]);
            dst = W2f;
        }
        *(unsigned*)&dst[(fg * 64 + lane) * 8 + j] = (unsigned)v0 | ((unsigned)v1 << 16);
        return;
    }

    __shared__ float row_lds[8][128];
    __shared__ float red[8][4];
    const int row0 = blockIdx.x * 8;
    const float* src = in_obs + row0 * DD;
    #pragma unroll
    for (int i = 0; i < 4; ++i) {
        int idx = t + i * 256;
        row_lds[idx >> 7][idx & 127] = src[idx];
    }
    __syncthreads();

    const int l0 = t, l1 = t + 256;
    float acc0[8], acc1[8];
    #pragma unroll
    for (int r = 0; r < 8; ++r) { acc0[r] = 0.f; acc1[r] = 0.f; }

    #pragma unroll 4
    for (int d = 0; d < 128; d += 4) {
        f4arr rbuf[8];
        #pragma unroll
        for (int r = 0; r < 8; ++r)
            rbuf[r] = *(const f4arr*)&row_lds[r][d];
        #pragma unroll
        for (int dd = 0; dd < 4; ++dd) {
            const float w0 = Wk_w[(d + dd) * LL + l0];
            const float w1 = Wk_w[(d + dd) * LL + l1];
            #pragma unroll
            for (int r = 0; r < 8; ++r) {
                acc0[r] += rbuf[r].v[dd] * w0;
                acc1[r] += rbuf[r].v[dd] * w1;
            }
        }
    }
    const float kb0 = Wk_b[l0], kb1 = Wk_b[l1];
    const float wv0 = wv_w[640 + l0], wv1 = wv_w[640 + l1];
    float v[8];
    #pragma unroll
    for (int r = 0; r < 8; ++r)
        v[r] = tanhf(acc0[r] + kb0) * wv0 + tanhf(acc1[r] + kb1) * wv1;
    #pragma unroll
    for (int off = 32; off > 0; off >>= 1) {
        #pragma unroll
        for (int r = 0; r < 8; ++r)
            v[r] += __shfl_down(v[r], off, 64);
    }
    if (lane == 0) {
        #pragma unroll
        for (int r = 0; r < 8; ++r) red[r][wave] = v[r];
    }
    __syncthreads();
    if (t < 8) {
        const int row = row0 + t;
        const int j = row & (NN - 1);
        c_out[row] = red[t][0] + red[t][1] + red[t][2] + red[t][3]
                   + TANH1 * wv_w[1152 + j];
    }
}

// ---------------------------------------------------------------------------
// kB: 256 blocks x 512 thr (1 block/CU), __launch_bounds__(512,2) -> 256
// VGPR budget, ALL 32 W-fragment loads prefetched back-to-back at entry.
// 8 real rows + 8 pad per M=16 tile. Verbatim R14 (best-measured).
// ---------------------------------------------------------------------------
__global__ __launch_bounds__(512, 2) void kB(
    const float* __restrict__ in_obs,
    const float* __restrict__ c_in,
    const unsigned short* __restrict__ W1f,
    const unsigned short* __restrict__ W2f,
    const float* __restrict__ g1, const float* __restrict__ b1,
    const float* __restrict__ ff1_b,
    const float* __restrict__ ff2_b,
    const float* __restrict__ g2, const float* __restrict__ b2,
    float* __restrict__ out)
{
    const int t = threadIdx.x;
    const int b = blockIdx.x >> 4;
    const int j0 = (blockIdx.x & 15) * 8;
    const int wave = t >> 6, lane = t & 63;
    const int l15 = lane & 15, l4 = lane >> 4;

    __shared__ float part[8][128];
    __shared__ alignas(16) unsigned short res_lds[16 * 128];
    __shared__ alignas(16) unsigned short h_lds[16 * 512];
    __shared__ alignas(16) float o2_lds[16 * 128];

    // ---- full fragment prefetch (32 b128 loads, back-to-back)
    bf16x8 a1p[16];
    #pragma unroll
    for (int i = 0; i < 4; ++i)
        #pragma unroll
        for (int ks = 0; ks < 4; ++ks)
            a1p[i * 4 + ks] =
                *(const bf16x8*)(W1f + (((wave * 4 + i) * 4 + ks) * 64 + lane) * 8);
    bf16x8 a2p[16];
    #pragma unroll
    for (int ks = 0; ks < 16; ++ks)
        a2p[ks] = *(const bf16x8*)(W2f + ((wave * 16 + ks) * 64 + lane) * 8);

    // ---- softmax fully in registers (per wave; q-side term cancels)
    const float cv0 = c_in[b * NN + lane];
    const float cv1 = c_in[b * NN + lane + 64];
    float mx = fmaxf(cv0, cv1);
    #pragma unroll
    for (int off = 32; off > 0; off >>= 1) mx = fmaxf(mx, __shfl_xor(mx, off, 64));
    float e0 = __expf(cv0 - mx), e1 = __expf(cv1 - mx);
    float sm = e0 + e1;
    #pragma unroll
    for (int off = 32; off > 0; off >>= 1) sm += __shfl_xor(sm, off, 64);
    const float inv = 1.f / sm;
    e0 *= inv; e1 *= inv;

    // ---- attn partials: wave w sums its 16 j's, both d-halves
    {
        const float* base = in_obs + (b * NN + wave * 16) * DD;
        float a0 = 0.f, a1 = 0.f;
        #pragma unroll
        for (int jj = 0; jj < 16; ++jj) {
            const int js = wave * 16 + jj;
            const float wj = (wave < 4) ? __shfl(e0, js, 64)
                                        : __shfl(e1, js - 64, 64);
            a0 += wj * base[jj * DD + lane];
            a1 += wj * base[jj * DD + 64 + lane];
        }
        part[wave][lane] = a0;
        part[wave][lane + 64] = a1;
    }
    __syncthreads();                               // B1

    // ---- residual + LN1 -> res_lds bf16 (wave w = row w; pad row w+8)
    {
        const int r = wave;
        const int row = b * NN + j0 + r;
        const int c0i = lane * 2;
        const float2 xo = *(const float2*)&in_obs[row * DD + c0i];
        float x0 = xo.x, x1 = xo.y;
        #pragma unroll
        for (int g = 0; g < 8; ++g) {
            const float2 p = *(const float2*)&part[g][c0i];
            x0 += p.x; x1 += p.y;
        }
        float s = x0 + x1;
        #pragma unroll
        for (int off = 32; off > 0; off >>= 1) s += __shfl_xor(s, off, 64);
        const float mu = s * (1.f / 128.f);
        const float d0 = x0 - mu, d1 = x1 - mu;
        float vs = d0 * d0 + d1 * d1;
        #pragma unroll
        for (int off = 32; off > 0; off >>= 1) vs += __shfl_xor(vs, off, 64);
        const float rstd = rsqrtf(vs * (1.f / 128.f) + 1e-5f);
        const float2 gv = *(const float2*)&g1[c0i];
        const float2 bv = *(const float2*)&b1[c0i];
        const float r0 = d0 * rstd * gv.x + bv.x;
        const float r1 = d1 * rstd * gv.y + bv.y;
        const unsigned pk = (unsigned)f2bf(r0) | ((unsigned)f2bf(r1) << 16);
        const int swz = (lane * 4) ^ ((r & 7) << 4);
        *(unsigned*)((char*)res_lds + r * 256 + swz) = pk;
        *(unsigned*)((char*)res_lds + (r + 8) * 256 + (lane * 4)) = 0u; // pad
    }
    __syncthreads();                               // B2

    // ---- FF1 swapped GEMM: wave does mt = wave*4 + {0..3}, frags in regs
    {
        bf16x8 bfrag[4];
        #pragma unroll
        for (int ks = 0; ks < 4; ++ks) {
            const int off = l15 * 256 + ((ks * 64 + l4 * 16) ^ ((l15 & 7) << 4));
            bfrag[ks] = *(const bf16x8*)((const char*)res_lds + off);
        }
        #pragma unroll
        for (int i = 0; i < 4; ++i) {
            const int mt = wave * 4 + i;
            f32x4 acc = {0.f, 0.f, 0.f, 0.f};
            #pragma unroll
            for (int ks = 0; ks < 4; ++ks)
                acc = __builtin_amdgcn_mfma_f32_16x16x32_bf16(
                          a1p[i * 4 + ks], bfrag[ks], acc, 0, 0, 0);
            const f4arr bias = *(const f4arr*)&ff1_b[mt * 16 + l4 * 4];
            uint2 pk;
            pk.x = (unsigned)f2bf(fmaxf(acc[0] + bias.v[0], 0.f))
                 | ((unsigned)f2bf(fmaxf(acc[1] + bias.v[1], 0.f)) << 16);
            pk.y = (unsigned)f2bf(fmaxf(acc[2] + bias.v[2], 0.f))
                 | ((unsigned)f2bf(fmaxf(acc[3] + bias.v[3], 0.f)) << 16);
            const int off = l15 * 1024 + ((mt * 32 + l4 * 8) ^ ((l15 & 7) << 4));
            *(uint2*)((char*)h_lds + off) = pk;
        }
    }
    __syncthreads();                               // B3

    // ---- FF2 swapped GEMM: wave = n-tile (0..7), full K, frags in regs
    {
        f32x4 acc = {0.f, 0.f, 0.f, 0.f};
        #pragma unroll
        for (int ks = 0; ks < 16; ++ks) {
            const int off = l15 * 1024 + ((ks * 64 + l4 * 16) ^ ((l15 & 7) << 4));
            const bf16x8 bfrag = *(const bf16x8*)((const char*)h_lds + off);
            acc = __builtin_amdgcn_mfma_f32_16x16x32_bf16(a2p[ks], bfrag, acc, 0, 0, 0);
        }
        const int off = l15 * 512 + ((wave * 64 + l4 * 16) ^ ((l15 & 7) << 4));
        *(f32x4*)((char*)o2_lds + off) = acc;
    }
    __syncthreads();                               // B4

    // ---- bias + residual + LN2 -> out (wave w = row w)
    {
        const int r = wave;
        const int row = b * NN + j0 + r;
        const int c0i = lane * 2;
        const int off = r * 512 + ((lane * 8) ^ ((r & 7) << 4));
        const float2 o2 = *(const float2*)((char*)o2_lds + off);
        const float2 fb = *(const float2*)&ff2_b[c0i];
        const float2 xo = *(const float2*)&in_obs[row * DD + c0i];
        const float f0 = o2.x + fb.x + xo.x;
        const float f1 = o2.y + fb.y + xo.y;
        float s = f0 + f1;
        #pragma unroll
        for (int off2 = 32; off2 > 0; off2 >>= 1) s += __shfl_xor(s, off2, 64);
        const float mu = s * (1.f / 128.f);
        const float d0 = f0 - mu, d1 = f1 - mu;
        float vs = d0 * d0 + d1 * d1;
        #pragma unroll
        for (int off2 = 32; off2 > 0; off2 >>= 1) vs += __shfl_xor(vs, off2, 64);
        const float rstd = rsqrtf(vs * (1.f / 128.f) + 1e-5f);
        const float2 gv = *(const float2*)&g2[c0i];
        const float2 bv = *(const float2*)&b2[c0i];
        float2 o;
        o.x = d0 * rstd * gv.x + bv.x;
        o.y = d1 * rstd * gv.y + bv.y;
        *(float2*)&out[row * DD + c0i] = o;
    }
}

extern "C" void kernel_launch(void* const* d_in, const int* in_sizes, int n_in,
                              void* d_out, int out_size, void* d_ws, size_t ws_size,
                              hipStream_t stream) {
    const float* in_obs = (const float*)d_in[0];
    // d_in[1] Wq_w, d_in[2] Wq_b, d_in[6] wv_b: dead (cancel in softmax)
    const float* Wk_w  = (const float*)d_in[3];
    const float* Wk_b  = (const float*)d_in[4];
    const float* wv_w  = (const float*)d_in[5];
    const float* g1    = (const float*)d_in[7];
    const float* b1    = (const float*)d_in[8];
    const float* ff1_w = (const float*)d_in[9];
    const float* ff1_b = (const float*)d_in[10];
    const float* ff2_w = (const float*)d_in[11];
    const float* ff2_b = (const float*)d_in[12];
    const float* g2    = (const float*)d_in[13];
    const float* b2    = (const float*)d_in[14];
    float* outp = (float*)d_out;

    unsigned short* W1f = (unsigned short*)d_ws;              // 128 KB
    unsigned short* W2f = W1f + 65536;                        // 128 KB
    float* c_ws = (float*)((char*)d_ws + 262144);             // 8 KB

    kA<<<512, 256, 0, stream>>>(in_obs, Wk_w, Wk_b, wv_w, ff1_w, ff2_w,
                                c_ws, W1f, W2f);
    kB<<<256, 512, 0, stream>>>(in_obs, c_ws, W1f, W2f, g1, b1,
                                ff1_b, ff2_b, g2, b2, outp);
}